// Round 26
// baseline (54.038 us; speedup 1.0000x reference)
//
#include <hip/hip_runtime.h>
#include <hip/hip_bf16.h>
#include <math.h>

typedef __attribute__((ext_vector_type(8)))  short short8;
typedef __attribute__((ext_vector_type(4)))  float floatx4;
typedef __attribute__((ext_vector_type(16))) float f32x16;

#define L_SEQ 2048
#define NHEADS 8
#define EDIM 64
#define PLANE (L_SEQ * EDIM) // shorts per (b,h) plane in workspace (131072)
#define LOG2E 1.4426950408889634f

union U8 { unsigned u[4]; short8 s; };

__device__ __forceinline__ unsigned cvt_pk(float lo, float hi) {
    unsigned r;
    asm("v_cvt_pk_bf16_f32 %0, %1, %2" : "=v"(r) : "v"(lo), "v"(hi));
    return r;
}
__device__ __forceinline__ short8 pack8(floatx4 a, floatx4 b) {
    U8 r;
    r.u[0] = cvt_pk(a[0], a[1]); r.u[1] = cvt_pk(a[2], a[3]);
    r.u[2] = cvt_pk(b[0], b[1]); r.u[3] = cvt_pk(b[2], b[3]);
    return r.s;
}
// bare hardware 2^x (libm exp2f without -ffast-math is a multi-op sequence)
__device__ __forceinline__ float fast_exp2(float x) {
    float r;
    asm("v_exp_f32 %0, %1" : "=v"(r) : "v"(x));
    return r;
}

// ---------- prep: K,V fp32 -> bf16 fragment-linear; bias table per head ----------
__global__ __launch_bounds__(256) void prep_frag(
    const float* __restrict__ K, const float* __restrict__ V,
    const float* __restrict__ table,
    unsigned short* __restrict__ Kf, unsigned short* __restrict__ Vf,
    float* __restrict__ Btab)
{
    __shared__ unsigned short Tk[64][72];   // [row][e]
    __shared__ unsigned short Tv[64][72];   // [e][k]
    const int st  = blockIdx.x;        // 64-seq-row tile (32 tiles)
    const int bh  = blockIdx.y;        // b*8+h
    const int b   = bh >> 3, h = bh & 7;
    const int tid = threadIdx.x;
    const int sb  = st * 64;

    // bias table (log2e-scaled), jnp fp32 op order: done by 8 blocks
    if (st == 0 && bh < 8) {
        for (int d = tid; d < L_SEQ; d += 256) {
            int bucket;
            if (d < 16) bucket = d;
            else {
                float t = logf((float)d * 0.0625f) / 2.0794415416798357f * 16.0f;
                int bb = 16 + (int)t;
                bucket = bb < 31 ? bb : 31;
            }
            Btab[bh * L_SEQ + d] = table[bucket * NHEADS + bh] * LOG2E;
        }
    }

    {   // load K rows coalesced -> Tk
        int s0 = tid >> 3, e0 = (tid & 7) * 8;
        #pragma unroll
        for (int j = 0; j < 2; ++j) {
            int s = s0 + j * 32;
            const float* kp = K + ((size_t)(b * L_SEQ + sb + s) * NHEADS + h) * EDIM + e0;
            floatx4 f0 = *(const floatx4*)kp;
            floatx4 f1 = *(const floatx4*)(kp + 4);
            *(short8*)&Tk[s][e0] = pack8(f0, f1);
        }
    }
    {   // load V rows coalesced (lane = e) -> Tv transposed
        int e = tid & 63, sg = tid >> 6;
        #pragma unroll
        for (int j = 0; j < 16; ++j) {
            int s = sg * 16 + j;
            float v = V[((size_t)(b * L_SEQ + sb + s) * NHEADS + h) * EDIM + e];
            union { float f; unsigned u; } cv; cv.f = v;
            Tv[e][s] = (unsigned short)((cv.u + 0x7FFFu + ((cv.u >> 16) & 1u)) >> 16);
        }
    }
    __syncthreads();
    {   // write Kf fragment-linear (coalesced)
        int s2 = tid >> 7, t7 = tid & 127, ec = t7 >> 5, l31 = t7 & 31;
        #pragma unroll
        for (int hi = 0; hi < 2; ++hi) {
            int row = s2 * 32 + l31, e = ec * 16 + hi * 8;
            short8 v = *(const short8*)&Tk[row][e];
            size_t unit = (((size_t)bh * 64 + st * 2 + s2) * 4 + ec) * 64 + hi * 32 + l31;
            *(short8*)&Kf[unit * 8] = v;
        }
    }
    {   // write Vf fragment-linear (coalesced)
        int s2 = tid >> 7, t7 = tid & 127, et = t7 >> 6, lane = t7 & 63;
        #pragma unroll
        for (int c = 0; c < 2; ++c) {
            int e = et * 32 + (lane & 31), k0 = s2 * 32 + c * 16 + (lane >> 5) * 8;
            short8 v = *(const short8*)&Tv[e][k0];
            size_t unit = ((((size_t)bh * 64 + st * 2 + s2) * 2 + et) * 2 + c) * 64 + lane;
            *(short8*)&Vf[unit * 8] = v;
        }
    }
}

// ---------- attention: dual q-groups share K/V loads; branchless 2-deep prefetch ----------
__global__ __launch_bounds__(256, 2) void attn_fwd(
    const float* __restrict__ Q, const unsigned short* __restrict__ Kf,
    const unsigned short* __restrict__ Vf, const float* __restrict__ Btab,
    float* __restrict__ Out)
{
    __shared__ __align__(16) float bias_lds[L_SEQ];   // 8 KB (log2e-scaled)
    __shared__ __align__(16) float osc[2][32][64];    // 16 KB merge scratch, lane-major
    __shared__ float lsc[2][2][16];                   // l merge: [slot][hi][r]

    // XCD-aware swizzle: 512 blocks; XCD x owns bh in [4x,4x+4) -> 2 MB K/V in its L2.
    const int bid  = blockIdx.x;
    const int wid  = (bid & 7) * 64 + (bid >> 3);
    const int bh   = wid >> 4;                 // 0..31
    const int pj   = wid & 15;                 // adjacent-pair index 0..15
    const int b    = bh >> 3, h = bh & 7;
    const int tid  = threadIdx.x;
    const int w    = tid >> 6, lane = tid & 63;
    const int q32  = lane & 31;
    const int hi   = lane >> 5;
    const int hi4  = 4 * hi, hi8 = 8 * hi;

    // bias: bulk copy (max range over both passes), coalesced float4 from L2
    const int n0 = 2 * pj + 2, n1 = 64 - 2 * pj;
    const int nmax = n0 > n1 ? n0 : n1;        // >= 33
    const int dmax4 = (32 * nmax) >> 2;
    const floatx4* bt = (const floatx4*)(Btab + h * L_SEQ);
    for (int i = tid; i < dmax4; i += 256)
        ((floatx4*)bias_lds)[i] = bt[i];
    __syncthreads();    // bias ready

    // bucket(d) saturates to 31 for d >= 113 -> one constant for "far" tiles
    const float cbias = Btab[h * L_SEQ + 1024];

    const unsigned short* kfb = Kf + (size_t)bh * PLANE + lane * 8;
    const unsigned short* vfb = Vf + (size_t)bh * PLANE + lane * 8;

    U8 onesf;
    onesf.u[0] = 0x3F803F80u; onesf.u[1] = 0x3F803F80u;
    onesf.u[2] = 0x3F803F80u; onesf.u[3] = 0x3F803F80u;

    const float qscale = 0.125f * LOG2E;

    // softmax + PV for one group (unnormalized, no max-tracking; see r5/r14)
    auto sm_pv = [&](const f32x16& st, int qrowX, int qgX, int s32,
                     f32x16* o_acc, f32x16& o_l,
                     short8 v0, short8 v1, short8 v2, short8 v3) {
        const int kv0s = s32 * 32;
        float p[16];
        if (s32 <= qgX - 5) {                 // saturated-bucket region: reg constant
            #pragma unroll
            for (int r = 0; r < 16; ++r)
                p[r] = fast_exp2(fmaf(qscale, st[r], cbias));
        } else if (s32 != qgX) {
            const float* bptr = &bias_lds[qrowX - kv0s - hi4];
            #pragma unroll
            for (int r = 0; r < 16; ++r)
                p[r] = fast_exp2(fmaf(qscale, st[r], bptr[-(r & 3) - 8 * (r >> 2)]));
        } else {                              // diagonal: causal mask -> 0
            #pragma unroll
            for (int r = 0; r < 16; ++r) {
                int kidx = (r & 3) + 8 * (r >> 2) + hi4;
                int d = q32 - kidx;
                int dc = d < 0 ? 0 : d;
                float ex = fast_exp2(fmaf(qscale, st[r], bias_lds[dc]));
                p[r] = (d >= 0) ? ex : 0.0f;
            }
        }
        // P -> bf16 A-fragments in-register via permlane32_swap (T12)
        unsigned x0 = cvt_pk(p[0],  p[1]),  x1 = cvt_pk(p[2],  p[3]);
        unsigned y0 = cvt_pk(p[4],  p[5]),  y1 = cvt_pk(p[6],  p[7]);
        unsigned x2 = cvt_pk(p[8],  p[9]),  x3 = cvt_pk(p[10], p[11]);
        unsigned y2 = cvt_pk(p[12], p[13]), y3 = cvt_pk(p[14], p[15]);
        asm("v_permlane32_swap_b32 %0, %1" : "+v"(x0), "+v"(y0));
        asm("v_permlane32_swap_b32 %0, %1" : "+v"(x1), "+v"(y1));
        asm("v_permlane32_swap_b32 %0, %1" : "+v"(x2), "+v"(y2));
        asm("v_permlane32_swap_b32 %0, %1" : "+v"(x3), "+v"(y3));
        U8 pf0; pf0.u[0] = x0; pf0.u[1] = x1; pf0.u[2] = y0; pf0.u[3] = y1;
        U8 pf1; pf1.u[0] = x2; pf1.u[1] = x3; pf1.u[2] = y2; pf1.u[3] = y3;

        // O += P·V ; l += P·1
        o_acc[0] = __builtin_amdgcn_mfma_f32_32x32x16_bf16(pf0.s, v0, o_acc[0], 0, 0, 0);
        o_acc[0] = __builtin_amdgcn_mfma_f32_32x32x16_bf16(pf1.s, v1, o_acc[0], 0, 0, 0);
        o_acc[1] = __builtin_amdgcn_mfma_f32_32x32x16_bf16(pf0.s, v2, o_acc[1], 0, 0, 0);
        o_acc[1] = __builtin_amdgcn_mfma_f32_32x32x16_bf16(pf1.s, v3, o_acc[1], 0, 0, 0);
        o_l      = __builtin_amdgcn_mfma_f32_32x32x16_bf16(pf0.s, onesf.s, o_l, 0, 0, 0);
        o_l      = __builtin_amdgcn_mfma_f32_32x32x16_bf16(pf1.s, onesf.s, o_l, 0, 0, 0);
    };

    // additive merge of the 4 kv-quarters + epilogue store for one group
    auto merge_store = [&](f32x16* o_acc, f32x16& o_l, int qsX) {
        __syncthreads();                     // previous scratch users done
        if (w & 1) {                         // waves 1,3 -> slots 0,1
            int slot = w >> 1;
            #pragma unroll
            for (int et = 0; et < 2; ++et)
                #pragma unroll
                for (int r = 0; r < 16; ++r)
                    osc[slot][et * 16 + r][lane] = o_acc[et][r];
            if (q32 == 0) {
                #pragma unroll
                for (int r = 0; r < 16; ++r) lsc[slot][hi][r] = o_l[r];
            }
        }
        __syncthreads();
        if (!(w & 1)) {                      // waves 0,2 absorb
            int slot = w >> 1;
            #pragma unroll
            for (int et = 0; et < 2; ++et)
                #pragma unroll
                for (int r = 0; r < 16; ++r)
                    o_acc[et][r] += osc[slot][et * 16 + r][lane];
            #pragma unroll
            for (int r = 0; r < 16; ++r) o_l[r] += lsc[slot][hi][r];
        }
        __syncthreads();
        if (w == 2) {                        // wave 2 -> slot 0
            #pragma unroll
            for (int et = 0; et < 2; ++et)
                #pragma unroll
                for (int r = 0; r < 16; ++r)
                    osc[0][et * 16 + r][lane] = o_acc[et][r];
            if (q32 == 0) {
                #pragma unroll
                for (int r = 0; r < 16; ++r) lsc[0][hi][r] = o_l[r];
            }
        }
        __syncthreads();
        if (w == 0) {
            #pragma unroll
            for (int et = 0; et < 2; ++et)
                #pragma unroll
                for (int r = 0; r < 16; ++r)
                    o_acc[et][r] += osc[0][et * 16 + r][lane];
            #pragma unroll
            for (int r = 0; r < 16; ++r) o_l[r] += lsc[0][hi][r];

            // epilogue: O / l ; l already in C-row layout -> direct division
            #pragma unroll
            for (int r = 0; r < 16; ++r) {
                int qv = (r & 3) + 8 * (r >> 2) + hi4;
                float iv = 1.0f / o_l[r];
                float* op = Out + ((size_t)(b * L_SEQ + qsX + qv) * NHEADS + h) * EDIM + q32;
                op[0]  = o_acc[0][r] * iv;
                op[32] = o_acc[1][r] * iv;
            }
        }
    };

    #pragma unroll 1
    for (int pass = 0; pass < 2; ++pass) {
        const int g0   = pass ? (62 - 2 * pj) : (2 * pj);
        const int qgA  = g0, qgB = g0 + 1;    // adjacent groups share kv loads
        const int qsA  = qgA * 32, qsB = qgB * 32;
        const int qrowA = qsA + q32, qrowB = qsB + q32;
        const int nsub = qgB + 1;             // B's (larger) kv range

        // Q B-fragments for both groups
        const float* qpA = Q + ((size_t)(b * L_SEQ + qrowA) * NHEADS + h) * EDIM;
        const float* qpB = Q + ((size_t)(b * L_SEQ + qrowB) * NHEADS + h) * EDIM;
        short8 qfragA[4], qfragB[4];
        #pragma unroll
        for (int ec = 0; ec < 4; ++ec) {
            floatx4 a0 = *(const floatx4*)(qpA + ec * 16 + hi8);
            floatx4 a1 = *(const floatx4*)(qpA + ec * 16 + hi8 + 4);
            qfragA[ec] = pack8(a0, a1);
            floatx4 b0 = *(const floatx4*)(qpB + ec * 16 + hi8);
            floatx4 b1 = *(const floatx4*)(qpB + ec * 16 + hi8 + 4);
            qfragB[ec] = pack8(b0, b1);
        }

        const int len = (nsub + 3) >> 2;
        const int r0  = w * len;
        const int r1  = (r0 + len < nsub) ? r0 + len : nsub;
        const int cnt = r1 - r0;
        const int last = r1 - 1;

        f32x16 oA[2] = {}, oB[2] = {};
        f32x16 olA = {}, olB = {};

        // compute one subtile with a given fragment set (fully inlined)
        auto compute = [&](short8 kf0, short8 kf1, short8 kf2, short8 kf3,
                           short8 vv0, short8 vv1, short8 vv2, short8 vv3, int s32) {
            const bool doA = (s32 <= qgA);
            f32x16 stB = {};
            stB = __builtin_amdgcn_mfma_f32_32x32x16_bf16(kf0, qfragB[0], stB, 0, 0, 0);
            stB = __builtin_amdgcn_mfma_f32_32x32x16_bf16(kf1, qfragB[1], stB, 0, 0, 0);
            stB = __builtin_amdgcn_mfma_f32_32x32x16_bf16(kf2, qfragB[2], stB, 0, 0, 0);
            stB = __builtin_amdgcn_mfma_f32_32x32x16_bf16(kf3, qfragB[3], stB, 0, 0, 0);
            f32x16 stA = {};
            if (doA) {
                stA = __builtin_amdgcn_mfma_f32_32x32x16_bf16(kf0, qfragA[0], stA, 0, 0, 0);
                stA = __builtin_amdgcn_mfma_f32_32x32x16_bf16(kf1, qfragA[1], stA, 0, 0, 0);
                stA = __builtin_amdgcn_mfma_f32_32x32x16_bf16(kf2, qfragA[2], stA, 0, 0, 0);
                stA = __builtin_amdgcn_mfma_f32_32x32x16_bf16(kf3, qfragA[3], stA, 0, 0, 0);
            }
            sm_pv(stB, qrowB, qgB, s32, oB, olB, vv0, vv1, vv2, vv3);
            if (doA) sm_pv(stA, qrowA, qgA, s32, oA, olA, vv0, vv1, vv2, vv3);
        };

        if (cnt > 0) {
            // ping-pong fragment sets; all prefetches branchless (clamped index)
            short8 ka0, ka1, ka2, ka3, va0, va1, va2, va3;
            short8 kb0, kb1, kb2, kb3, vb0, vb1, vb2, vb3;
            {   // prologue: load set A <- r0
                const unsigned short* kp = kfb + (size_t)r0 * 2048;
                const unsigned short* vp = vfb + (size_t)r0 * 2048;
                ka0 = *(const short8*)(kp);        ka1 = *(const short8*)(kp + 512);
                ka2 = *(const short8*)(kp + 1024); ka3 = *(const short8*)(kp + 1536);
                va0 = *(const short8*)(vp);        va1 = *(const short8*)(vp + 512);
                va2 = *(const short8*)(vp + 1024); va3 = *(const short8*)(vp + 1536);
            }
            int i = 0;
            for (; i + 2 <= cnt; i += 2) {
                {   // prefetch set B <- i+1 (always valid here)
                    const unsigned short* kp = kfb + (size_t)(r0 + i + 1) * 2048;
                    const unsigned short* vp = vfb + (size_t)(r0 + i + 1) * 2048;
                    kb0 = *(const short8*)(kp);        kb1 = *(const short8*)(kp + 512);
                    kb2 = *(const short8*)(kp + 1024); kb3 = *(const short8*)(kp + 1536);
                    vb0 = *(const short8*)(vp);        vb1 = *(const short8*)(vp + 512);
                    vb2 = *(const short8*)(vp + 1024); vb3 = *(const short8*)(vp + 1536);
                }
                compute(ka0, ka1, ka2, ka3, va0, va1, va2, va3, r0 + i);
                {   // prefetch set A <- clamp(i+2) -- branchless; redundant on last iter
                    int nx = r0 + i + 2; nx = nx > last ? last : nx;
                    const unsigned short* kp = kfb + (size_t)nx * 2048;
                    const unsigned short* vp = vfb + (size_t)nx * 2048;
                    ka0 = *(const short8*)(kp);        ka1 = *(const short8*)(kp + 512);
                    ka2 = *(const short8*)(kp + 1024); ka3 = *(const short8*)(kp + 1536);
                    va0 = *(const short8*)(vp);        va1 = *(const short8*)(vp + 512);
                    va2 = *(const short8*)(vp + 1024); va3 = *(const short8*)(vp + 1536);
                }
                compute(kb0, kb1, kb2, kb3, vb0, vb1, vb2, vb3, r0 + i + 1);
            }
            if (i < cnt)
                compute(ka0, ka1, ka2, ka3, va0, va1, va2, va3, r0 + i);
        }

        merge_store(oA, olA, qsA);
        merge_store(oB, olB, qsB);
    }
}

extern "C" void kernel_launch(void* const* d_in, const int* in_sizes, int n_in,
                              void* d_out, int out_size, void* d_ws, size_t ws_size,
                              hipStream_t stream) {
    const float* Q     = (const float*)d_in[0];
    const float* K     = (const float*)d_in[1];
    const float* V     = (const float*)d_in[2];
    const float* table = (const float*)d_in[3];
    float* Out = (float*)d_out;
    unsigned short* Kf = (unsigned short*)d_ws;                 // 8.4 MB
    unsigned short* Vf = Kf + (size_t)4 * NHEADS * PLANE;       // 8.4 MB
    float* Btab = (float*)(Vf + (size_t)4 * NHEADS * PLANE);    // 64 KB
    (void)in_sizes; (void)n_in; (void)out_size; (void)ws_size;

    dim3 pgrid(32, 32);
    prep_frag<<<pgrid, 256, 0, stream>>>(K, V, table, Kf, Vf, Btab);
    attn_fwd<<<dim3(512), 256, 0, stream>>>(Q, Kf, Vf, Btab, Out);
}

// Round 27
// 51.759 us; speedup vs baseline: 1.0440x; 1.0440x over previous
//
#include <hip/hip_runtime.h>
#include <hip/hip_bf16.h>
#include <math.h>

typedef __attribute__((ext_vector_type(8)))  short short8;
typedef __attribute__((ext_vector_type(4)))  float floatx4;
typedef __attribute__((ext_vector_type(16))) float f32x16;

#define L_SEQ 2048
#define NHEADS 8
#define EDIM 64
#define PLANE (L_SEQ * EDIM) // shorts per (b,h) plane in workspace (131072)
#define LOG2E 1.4426950408889634f

union U8 { unsigned u[4]; short8 s; };

__device__ __forceinline__ unsigned cvt_pk(float lo, float hi) {
    unsigned r;
    asm("v_cvt_pk_bf16_f32 %0, %1, %2" : "=v"(r) : "v"(lo), "v"(hi));
    return r;
}
__device__ __forceinline__ short8 pack8(floatx4 a, floatx4 b) {
    U8 r;
    r.u[0] = cvt_pk(a[0], a[1]); r.u[1] = cvt_pk(a[2], a[3]);
    r.u[2] = cvt_pk(b[0], b[1]); r.u[3] = cvt_pk(b[2], b[3]);
    return r.s;
}
// bare hardware 2^x (libm exp2f without -ffast-math is a multi-op sequence)
__device__ __forceinline__ float fast_exp2(float x) {
    float r;
    asm("v_exp_f32 %0, %1" : "=v"(r) : "v"(x));
    return r;
}

// ---------- prep: K,V fp32 -> bf16 fragment-linear; bias table per head ----------
__global__ __launch_bounds__(256) void prep_frag(
    const float* __restrict__ K, const float* __restrict__ V,
    const float* __restrict__ table,
    unsigned short* __restrict__ Kf, unsigned short* __restrict__ Vf,
    float* __restrict__ Btab)
{
    __shared__ unsigned short Tk[64][72];   // [row][e]
    __shared__ unsigned short Tv[64][72];   // [e][k]
    const int st  = blockIdx.x;        // 64-seq-row tile (32 tiles)
    const int bh  = blockIdx.y;        // b*8+h
    const int b   = bh >> 3, h = bh & 7;
    const int tid = threadIdx.x;
    const int sb  = st * 64;

    // bias table (log2e-scaled), jnp fp32 op order: done by 8 blocks
    if (st == 0 && bh < 8) {
        for (int d = tid; d < L_SEQ; d += 256) {
            int bucket;
            if (d < 16) bucket = d;
            else {
                float t = logf((float)d * 0.0625f) / 2.0794415416798357f * 16.0f;
                int bb = 16 + (int)t;
                bucket = bb < 31 ? bb : 31;
            }
            Btab[bh * L_SEQ + d] = table[bucket * NHEADS + bh] * LOG2E;
        }
    }

    {   // load K rows coalesced -> Tk
        int s0 = tid >> 3, e0 = (tid & 7) * 8;
        #pragma unroll
        for (int j = 0; j < 2; ++j) {
            int s = s0 + j * 32;
            const float* kp = K + ((size_t)(b * L_SEQ + sb + s) * NHEADS + h) * EDIM + e0;
            floatx4 f0 = *(const floatx4*)kp;
            floatx4 f1 = *(const floatx4*)(kp + 4);
            *(short8*)&Tk[s][e0] = pack8(f0, f1);
        }
    }
    {   // load V rows coalesced (lane = e) -> Tv transposed
        int e = tid & 63, sg = tid >> 6;
        #pragma unroll
        for (int j = 0; j < 16; ++j) {
            int s = sg * 16 + j;
            float v = V[((size_t)(b * L_SEQ + sb + s) * NHEADS + h) * EDIM + e];
            union { float f; unsigned u; } cv; cv.f = v;
            Tv[e][s] = (unsigned short)((cv.u + 0x7FFFu + ((cv.u >> 16) & 1u)) >> 16);
        }
    }
    __syncthreads();
    {   // write Kf fragment-linear (coalesced)
        int s2 = tid >> 7, t7 = tid & 127, ec = t7 >> 5, l31 = t7 & 31;
        #pragma unroll
        for (int hi = 0; hi < 2; ++hi) {
            int row = s2 * 32 + l31, e = ec * 16 + hi * 8;
            short8 v = *(const short8*)&Tk[row][e];
            size_t unit = (((size_t)bh * 64 + st * 2 + s2) * 4 + ec) * 64 + hi * 32 + l31;
            *(short8*)&Kf[unit * 8] = v;
        }
    }
    {   // write Vf fragment-linear (coalesced)
        int s2 = tid >> 7, t7 = tid & 127, et = t7 >> 6, lane = t7 & 63;
        #pragma unroll
        for (int c = 0; c < 2; ++c) {
            int e = et * 32 + (lane & 31), k0 = s2 * 32 + c * 16 + (lane >> 5) * 8;
            short8 v = *(const short8*)&Tv[e][k0];
            size_t unit = ((((size_t)bh * 64 + st * 2 + s2) * 2 + et) * 2 + c) * 64 + lane;
            *(short8*)&Vf[unit * 8] = v;
        }
    }
}

// ---------- attention: 2 adjacent q-groups share each K/V load; causal-paired passes ----------
__global__ __launch_bounds__(256, 2) void attn_fwd(
    const float* __restrict__ Q, const unsigned short* __restrict__ Kf,
    const unsigned short* __restrict__ Vf, const float* __restrict__ Btab,
    float* __restrict__ Out)
{
    __shared__ __align__(16) float bias_lds[L_SEQ];   // 8 KB (log2e-scaled)
    __shared__ __align__(16) float osc[2][32][64];    // 16 KB merge scratch, lane-major
    __shared__ float lsc[2][2][16];                   // l merge: [slot][hi][r]

    // XCD-aware swizzle: 512 blocks; XCD x owns bh in [4x,4x+4) -> 2 MB K/V in its L2.
    const int bid  = blockIdx.x;
    const int wid  = (bid & 7) * 64 + (bid >> 3);
    const int bh   = wid >> 4;                 // 0..31
    const int pj   = wid & 15;                 // adjacent-pair index 0..15
    const int b    = bh >> 3, h = bh & 7;
    const int tid  = threadIdx.x;
    const int w    = tid >> 6, lane = tid & 63;
    const int q32  = lane & 31;
    const int hi   = lane >> 5;
    const int hi4  = 4 * hi, hi8 = 8 * hi;

    // bias: bulk copy (max range over both passes), coalesced float4 from L2
    const int n0 = 2 * pj + 2, n1 = 64 - 2 * pj;
    const int nmax = n0 > n1 ? n0 : n1;        // >= 33
    const int dmax4 = (32 * nmax) >> 2;
    const floatx4* bt = (const floatx4*)(Btab + h * L_SEQ);
    for (int i = tid; i < dmax4; i += 256)
        ((floatx4*)bias_lds)[i] = bt[i];
    __syncthreads();    // bias ready

    // bucket(d) saturates to 31 for d >= 113 -> one constant for "far" tiles
    const float cbias = Btab[h * L_SEQ + 1024];

    const unsigned short* kfb = Kf + (size_t)bh * PLANE + lane * 8;
    const unsigned short* vfb = Vf + (size_t)bh * PLANE + lane * 8;

    U8 onesf;
    onesf.u[0] = 0x3F803F80u; onesf.u[1] = 0x3F803F80u;
    onesf.u[2] = 0x3F803F80u; onesf.u[3] = 0x3F803F80u;

    const float qscale = 0.125f * LOG2E;

    short8 vf0, vf1, vf2, vf3;   // shared V fragments (captured by sm_pv)

    // softmax + PV for one group (unnormalized, no max-tracking; see r5/r14)
    auto sm_pv = [&](const f32x16& st, int qrowX, int qgX, int s32,
                     f32x16* o_acc, f32x16& o_l) {
        const int kv0s = s32 * 32;
        float p[16];
        if (s32 <= qgX - 5) {                 // saturated-bucket region: reg constant
            #pragma unroll
            for (int r = 0; r < 16; ++r)
                p[r] = fast_exp2(fmaf(qscale, st[r], cbias));
        } else if (s32 != qgX) {
            const float* bptr = &bias_lds[qrowX - kv0s - hi4];
            #pragma unroll
            for (int r = 0; r < 16; ++r)
                p[r] = fast_exp2(fmaf(qscale, st[r], bptr[-(r & 3) - 8 * (r >> 2)]));
        } else {                              // diagonal: causal mask -> 0
            #pragma unroll
            for (int r = 0; r < 16; ++r) {
                int kidx = (r & 3) + 8 * (r >> 2) + hi4;
                int d = q32 - kidx;
                int dc = d < 0 ? 0 : d;
                float ex = fast_exp2(fmaf(qscale, st[r], bias_lds[dc]));
                p[r] = (d >= 0) ? ex : 0.0f;
            }
        }
        // P -> bf16 A-fragments in-register via permlane32_swap (T12)
        unsigned x0 = cvt_pk(p[0],  p[1]),  x1 = cvt_pk(p[2],  p[3]);
        unsigned y0 = cvt_pk(p[4],  p[5]),  y1 = cvt_pk(p[6],  p[7]);
        unsigned x2 = cvt_pk(p[8],  p[9]),  x3 = cvt_pk(p[10], p[11]);
        unsigned y2 = cvt_pk(p[12], p[13]), y3 = cvt_pk(p[14], p[15]);
        asm("v_permlane32_swap_b32 %0, %1" : "+v"(x0), "+v"(y0));
        asm("v_permlane32_swap_b32 %0, %1" : "+v"(x1), "+v"(y1));
        asm("v_permlane32_swap_b32 %0, %1" : "+v"(x2), "+v"(y2));
        asm("v_permlane32_swap_b32 %0, %1" : "+v"(x3), "+v"(y3));
        U8 pf0; pf0.u[0] = x0; pf0.u[1] = x1; pf0.u[2] = y0; pf0.u[3] = y1;
        U8 pf1; pf1.u[0] = x2; pf1.u[1] = x3; pf1.u[2] = y2; pf1.u[3] = y3;

        // O += P·V ; l += P·1
        o_acc[0] = __builtin_amdgcn_mfma_f32_32x32x16_bf16(pf0.s, vf0, o_acc[0], 0, 0, 0);
        o_acc[0] = __builtin_amdgcn_mfma_f32_32x32x16_bf16(pf1.s, vf1, o_acc[0], 0, 0, 0);
        o_acc[1] = __builtin_amdgcn_mfma_f32_32x32x16_bf16(pf0.s, vf2, o_acc[1], 0, 0, 0);
        o_acc[1] = __builtin_amdgcn_mfma_f32_32x32x16_bf16(pf1.s, vf3, o_acc[1], 0, 0, 0);
        o_l      = __builtin_amdgcn_mfma_f32_32x32x16_bf16(pf0.s, onesf.s, o_l, 0, 0, 0);
        o_l      = __builtin_amdgcn_mfma_f32_32x32x16_bf16(pf1.s, onesf.s, o_l, 0, 0, 0);
    };

    // additive merge of the 4 kv-quarters + epilogue store for one group
    auto merge_store = [&](f32x16* o_acc, f32x16& o_l, int qsX) {
        __syncthreads();                     // previous scratch users done
        if (w & 1) {                         // waves 1,3 -> slots 0,1
            int slot = w >> 1;
            #pragma unroll
            for (int et = 0; et < 2; ++et)
                #pragma unroll
                for (int r = 0; r < 16; ++r)
                    osc[slot][et * 16 + r][lane] = o_acc[et][r];
            if (q32 == 0) {
                #pragma unroll
                for (int r = 0; r < 16; ++r) lsc[slot][hi][r] = o_l[r];
            }
        }
        __syncthreads();
        if (!(w & 1)) {                      // waves 0,2 absorb
            int slot = w >> 1;
            #pragma unroll
            for (int et = 0; et < 2; ++et)
                #pragma unroll
                for (int r = 0; r < 16; ++r)
                    o_acc[et][r] += osc[slot][et * 16 + r][lane];
            #pragma unroll
            for (int r = 0; r < 16; ++r) o_l[r] += lsc[slot][hi][r];
        }
        __syncthreads();
        if (w == 2) {                        // wave 2 -> slot 0
            #pragma unroll
            for (int et = 0; et < 2; ++et)
                #pragma unroll
                for (int r = 0; r < 16; ++r)
                    osc[0][et * 16 + r][lane] = o_acc[et][r];
            if (q32 == 0) {
                #pragma unroll
                for (int r = 0; r < 16; ++r) lsc[0][hi][r] = o_l[r];
            }
        }
        __syncthreads();
        if (w == 0) {
            #pragma unroll
            for (int et = 0; et < 2; ++et)
                #pragma unroll
                for (int r = 0; r < 16; ++r)
                    o_acc[et][r] += osc[0][et * 16 + r][lane];
            #pragma unroll
            for (int r = 0; r < 16; ++r) o_l[r] += lsc[0][hi][r];

            // epilogue: O / l ; l already in C-row layout -> direct division
            #pragma unroll
            for (int r = 0; r < 16; ++r) {
                int qv = (r & 3) + 8 * (r >> 2) + hi4;
                float iv = 1.0f / o_l[r];
                float* op = Out + ((size_t)(b * L_SEQ + qsX + qv) * NHEADS + h) * EDIM + q32;
                op[0]  = o_acc[0][r] * iv;
                op[32] = o_acc[1][r] * iv;
            }
        }
    };

    #pragma unroll 1
    for (int pass = 0; pass < 2; ++pass) {
        const int g0   = pass ? (62 - 2 * pj) : (2 * pj);
        const int qgA  = g0, qgB = g0 + 1;    // adjacent groups share kv loads
        const int qsA  = qgA * 32, qsB = qgB * 32;
        const int qrowA = qsA + q32, qrowB = qsB + q32;
        const int nsub = qgB + 1;             // B's (larger) kv range

        // Q B-fragments for both groups
        const float* qpA = Q + ((size_t)(b * L_SEQ + qrowA) * NHEADS + h) * EDIM;
        const float* qpB = Q + ((size_t)(b * L_SEQ + qrowB) * NHEADS + h) * EDIM;
        short8 qfragA[4], qfragB[4];
        #pragma unroll
        for (int ec = 0; ec < 4; ++ec) {
            floatx4 a0 = *(const floatx4*)(qpA + ec * 16 + hi8);
            floatx4 a1 = *(const floatx4*)(qpA + ec * 16 + hi8 + 4);
            qfragA[ec] = pack8(a0, a1);
            floatx4 b0 = *(const floatx4*)(qpB + ec * 16 + hi8);
            floatx4 b1 = *(const floatx4*)(qpB + ec * 16 + hi8 + 4);
            qfragB[ec] = pack8(b0, b1);
        }

        const int len = (nsub + 3) >> 2;
        const int r0  = w * len;
        const int r1  = (r0 + len < nsub) ? r0 + len : nsub;

        f32x16 oA[2] = {}, oB[2] = {};
        f32x16 olA = {}, olB = {};

        for (int s32 = r0; s32 < r1; ++s32) {
            // one shared K/V load batch feeds both q-groups
            const unsigned short* kp = kfb + (size_t)s32 * 2048;
            const unsigned short* vp = vfb + (size_t)s32 * 2048;
            short8 kf0 = *(const short8*)(kp);
            short8 kf1 = *(const short8*)(kp + 512);
            short8 kf2 = *(const short8*)(kp + 1024);
            short8 kf3 = *(const short8*)(kp + 1536);
            vf0 = *(const short8*)(vp);
            vf1 = *(const short8*)(vp + 512);
            vf2 = *(const short8*)(vp + 1024);
            vf3 = *(const short8*)(vp + 1536);

            const bool doA = (s32 <= qgA);    // A masked past its diagonal

            f32x16 stB = {};
            stB = __builtin_amdgcn_mfma_f32_32x32x16_bf16(kf0, qfragB[0], stB, 0, 0, 0);
            stB = __builtin_amdgcn_mfma_f32_32x32x16_bf16(kf1, qfragB[1], stB, 0, 0, 0);
            stB = __builtin_amdgcn_mfma_f32_32x32x16_bf16(kf2, qfragB[2], stB, 0, 0, 0);
            stB = __builtin_amdgcn_mfma_f32_32x32x16_bf16(kf3, qfragB[3], stB, 0, 0, 0);
            f32x16 stA = {};
            if (doA) {
                stA = __builtin_amdgcn_mfma_f32_32x32x16_bf16(kf0, qfragA[0], stA, 0, 0, 0);
                stA = __builtin_amdgcn_mfma_f32_32x32x16_bf16(kf1, qfragA[1], stA, 0, 0, 0);
                stA = __builtin_amdgcn_mfma_f32_32x32x16_bf16(kf2, qfragA[2], stA, 0, 0, 0);
                stA = __builtin_amdgcn_mfma_f32_32x32x16_bf16(kf3, qfragA[3], stA, 0, 0, 0);
            }

            sm_pv(stB, qrowB, qgB, s32, oB, olB);
            if (doA) sm_pv(stA, qrowA, qgA, s32, oA, olA);
        }

        merge_store(oA, olA, qsA);
        merge_store(oB, olB, qsB);
    }
}

extern "C" void kernel_launch(void* const* d_in, const int* in_sizes, int n_in,
                              void* d_out, int out_size, void* d_ws, size_t ws_size,
                              hipStream_t stream) {
    const float* Q     = (const float*)d_in[0];
    const float* K     = (const float*)d_in[1];
    const float* V     = (const float*)d_in[2];
    const float* table = (const float*)d_in[3];
    float* Out = (float*)d_out;
    unsigned short* Kf = (unsigned short*)d_ws;                 // 8.4 MB
    unsigned short* Vf = Kf + (size_t)4 * NHEADS * PLANE;       // 8.4 MB
    float* Btab = (float*)(Vf + (size_t)4 * NHEADS * PLANE);    // 64 KB
    (void)in_sizes; (void)n_in; (void)out_size; (void)ws_size;

    dim3 pgrid(32, 32);
    prep_frag<<<pgrid, 256, 0, stream>>>(K, V, table, Kf, Vf, Btab);
    attn_fwd<<<dim3(512), 256, 0, stream>>>(Q, Kf, Vf, Btab, Out);
}